// Round 5
// baseline (124.543 us; speedup 1.0000x reference)
//
#include <hip/hip_runtime.h>

#define TOKENS 8192
#define EXPERTS 64
#define HIDDEN 4096

typedef __attribute__((ext_vector_type(8))) short bf16x8;
typedef __attribute__((ext_vector_type(4))) float f32x4;

// round-to-nearest-even f32 -> bf16 bits
__device__ __forceinline__ unsigned short bf16_rne(float f) {
    unsigned u = __float_as_uint(f);
    unsigned r = (u + 0x7FFFu + ((u >> 16) & 1u)) >> 16;
    return (unsigned short)r;
}

// ---------------------------------------------------------------------------
// Kernel A: split w (f32) into hi/lo bf16 planes, row-major [e][k] (B-frag ready)
// ---------------------------------------------------------------------------
__global__ void prep_w(const float* __restrict__ w,
                       unsigned short* __restrict__ wh,
                       unsigned short* __restrict__ wl) {
    const int i = blockIdx.x * 256 + threadIdx.x;   // 64*4096 elems
    const float f = w[i];
    const unsigned short hb = bf16_rne(f);
    const float hf = __uint_as_float(((unsigned)hb) << 16);
    wh[i] = hb;
    wl[i] = bf16_rne(f - hf);
}

// ---------------------------------------------------------------------------
// Main fused kernel: logits (3-pass bf16 MFMA) + softmax + top-8 + outputs.
// Grid 256 blocks x 32 tokens. 4 waves split K (1024 each).
// Per wave: M=32 (2 frags) x N=64 (4 frags), acc f32.
// A (x) loaded f32 from HBM, split to bf16 hi/lo in-reg. B pre-split in L2.
// ---------------------------------------------------------------------------
__device__ __forceinline__ void load_chunk(const float* xp0, const float* xp1,
                                           const unsigned short* bh0,
                                           const unsigned short* bl0, int koff,
                                           float4 (&A)[2][2], uint4 (&Bh)[4],
                                           uint4 (&Bl)[4]) {
    A[0][0] = *(const float4*)(xp0 + koff);
    A[0][1] = *(const float4*)(xp0 + koff + 4);
    A[1][0] = *(const float4*)(xp1 + koff);
    A[1][1] = *(const float4*)(xp1 + koff + 4);
#pragma unroll
    for (int n = 0; n < 4; ++n) {
        Bh[n] = *(const uint4*)(bh0 + (size_t)n * 16 * HIDDEN + koff);
        Bl[n] = *(const uint4*)(bl0 + (size_t)n * 16 * HIDDEN + koff);
    }
}

__device__ __forceinline__ void comp_chunk(const float4 (&A)[2][2],
                                           const uint4 (&Bh)[4],
                                           const uint4 (&Bl)[4],
                                           f32x4 (&acc)[2][4]) {
    bf16x8 ah[2], al[2];
#pragma unroll
    for (int m = 0; m < 2; ++m) {
        const float* f = (const float*)&A[m][0];
        bf16x8 h, l;
#pragma unroll
        for (int j = 0; j < 8; ++j) {
            const float xv = f[j];
            const unsigned short hb = bf16_rne(xv);
            const float hf = __uint_as_float(((unsigned)hb) << 16);
            h[j] = (short)hb;
            l[j] = (short)bf16_rne(xv - hf);
        }
        ah[m] = h; al[m] = l;
    }
#pragma unroll
    for (int n = 0; n < 4; ++n) {
        const bf16x8 bh = *(const bf16x8*)&Bh[n];
        const bf16x8 bl = *(const bf16x8*)&Bl[n];
#pragma unroll
        for (int m = 0; m < 2; ++m) {
            acc[m][n] = __builtin_amdgcn_mfma_f32_16x16x32_bf16(ah[m], bh, acc[m][n], 0, 0, 0);
            acc[m][n] = __builtin_amdgcn_mfma_f32_16x16x32_bf16(ah[m], bl, acc[m][n], 0, 0, 0);
            acc[m][n] = __builtin_amdgcn_mfma_f32_16x16x32_bf16(al[m], bh, acc[m][n], 0, 0, 0);
        }
    }
}

__global__ __launch_bounds__(256)
void router_main(const float* __restrict__ x,
                 const unsigned short* __restrict__ whb,
                 const unsigned short* __restrict__ wlb,
                 float* __restrict__ out,
                 int* __restrict__ flag_cnt,
                 int* __restrict__ flag_list) {
    __shared__ float lds[4][32][66];      // 33.8 KB
    const int tid = threadIdx.x;
    const int w = tid >> 6;
    const int lane = tid & 63;
    const int g = lane >> 4;              // k-subgroup / token-subgroup
    const int c = lane & 15;              // row (A) / col (B) within frag
    const int t0 = blockIdx.x * 32;
    const int kbase = w * (HIDDEN / 4);   // wave's K segment

    f32x4 acc[2][4];
#pragma unroll
    for (int m = 0; m < 2; ++m)
#pragma unroll
        for (int n = 0; n < 4; ++n) acc[m][n] = (f32x4)0.0f;

    const float* xp0 = x + (size_t)(t0 + c) * HIDDEN + kbase + g * 8;
    const float* xp1 = xp0 + (size_t)16 * HIDDEN;
    const unsigned short* bh0 = whb + (size_t)c * HIDDEN + kbase + g * 8;
    const unsigned short* bl0 = wlb + (size_t)c * HIDDEN + kbase + g * 8;

    float4 A0[2][2], A1[2][2];
    uint4 Bh0[4], Bl0[4], Bh1[4], Bl1[4];
    load_chunk(xp0, xp1, bh0, bl0, 0, A0, Bh0, Bl0);
    load_chunk(xp0, xp1, bh0, bl0, 32, A1, Bh1, Bl1);

    for (int ck = 0; ck < 32; ck += 2) {
        comp_chunk(A0, Bh0, Bl0, acc);
        if (ck + 2 < 32) load_chunk(xp0, xp1, bh0, bl0, (ck + 2) * 32, A0, Bh0, Bl0);
        comp_chunk(A1, Bh1, Bl1, acc);
        if (ck + 3 < 32) load_chunk(xp0, xp1, bh0, bl0, (ck + 3) * 32, A1, Bh1, Bl1);
    }

    // ---- cross-wave reduce: C layout col=lane&15, row=(lane>>4)*4+reg ----
#pragma unroll
    for (int m = 0; m < 2; ++m)
#pragma unroll
        for (int n = 0; n < 4; ++n)
#pragma unroll
            for (int r = 0; r < 4; ++r)
                lds[w][m * 16 + g * 4 + r][n * 16 + c] = acc[m][n][r];
    __syncthreads();
#pragma unroll
    for (int i = 0; i < 8; ++i) {
        const int cell = tid * 8 + i;     // 0..2047
        const int t = cell >> 6, e = cell & 63;
        lds[0][t][e] = lds[0][t][e] + lds[1][t][e] + lds[2][t][e] + lds[3][t][e];
    }
    __syncthreads();

    // ---- softmax + top-9 + outputs: 4 tokens per wave-pass (16-lane groups) ----
#pragma unroll
    for (int p = 0; p < 2; ++p) {
        const int t = w * 8 + p * 4 + g;
        float v[4];
#pragma unroll
        for (int s = 0; s < 4; ++s) v[s] = lds[0][t][s * 16 + c];

        float mx = fmaxf(fmaxf(v[0], v[1]), fmaxf(v[2], v[3]));
#pragma unroll
        for (int off = 1; off < 16; off <<= 1) mx = fmaxf(mx, __shfl_xor(mx, off));
        float sum = 0.f;
#pragma unroll
        for (int s = 0; s < 4; ++s) { v[s] = __expf(v[s] - mx); sum += v[s]; }
#pragma unroll
        for (int off = 1; off < 16; off <<= 1) sum += __shfl_xor(sum, off);
        const float inv = 1.0f / sum;
#pragma unroll
        for (int s = 0; s < 4; ++s) v[s] *= inv;

        float cur[4] = {v[0], v[1], v[2], v[3]};
        unsigned selmask = 0;
        float v8 = 0.f, v9 = 0.f;
#pragma unroll
        for (int it = 0; it < 9; ++it) {
            float bv = cur[0];
            int be = c;                    // expert = s*16 + c, s=0
#pragma unroll
            for (int s = 1; s < 4; ++s)
                if (cur[s] > bv) { bv = cur[s]; be = s * 16 + c; }
#pragma unroll
            for (int off = 1; off < 16; off <<= 1) {
                const float ov = __shfl_xor(bv, off);
                const int oe = __shfl_xor(be, off);
                if (ov > bv || (ov == bv && oe < be)) { bv = ov; be = oe; }
            }
            if (it < 8) {
                if ((be & 15) == c) { cur[be >> 4] = -1.f; selmask |= 1u << (be >> 4); }
                if (it == 7) v8 = bv;
            } else {
                v9 = bv;
            }
        }
        // near-tie rescue flag (selection robustness)
        if (c == 0 && (v8 - v9) < v8 * 1e-3f) {
            const int idx = atomicAdd(flag_cnt, 1);
            flag_list[idx] = t0 + t;
        }
#pragma unroll
        for (int s = 0; s < 4; ++s) {
            const bool sel = (selmask >> s) & 1u;
            out[(size_t)(t0 + t) * 64 + s * 16 + c] = sel ? v[s] : 0.f;
            out[(size_t)TOKENS * 64 + (size_t)(t0 + t) * 64 + s * 16 + c] = sel ? 1.f : 0.f;
        }
    }
}

// ---------------------------------------------------------------------------
// Rescue: exact f32 recompute of flagged tokens (near-tie at rank 8/9).
// Fixed grid, grid-strides over device count. Overwrites both output rows.
// ---------------------------------------------------------------------------
__global__ __launch_bounds__(256)
void router_rescue(const float* __restrict__ x, const float* __restrict__ wgt,
                   float* __restrict__ out, const int* __restrict__ cnt,
                   const int* __restrict__ list) {
    __shared__ float xrow[HIDDEN];        // 16 KB
    __shared__ float lg[EXPERTS];
    const int tid = threadIdx.x;
    const int w = tid >> 6, lane = tid & 63;
    const int n = cnt[0];
    for (int i = blockIdx.x; i < n; i += 256) {
        const int t = list[i];
        __syncthreads();
        for (int j = tid; j < HIDDEN / 4; j += 256)
            ((float4*)xrow)[j] = ((const float4*)(x + (size_t)t * HIDDEN))[j];
        __syncthreads();
#pragma unroll 2
        for (int ei = 0; ei < 16; ++ei) {
            const int e = w * 16 + ei;
            const float* wr = wgt + (size_t)e * HIDDEN;
            float a = 0.f;
            for (int kk = 0; kk < HIDDEN; kk += 256) {
                const float4 xv = *(const float4*)(xrow + kk + lane * 4);
                const float4 wv = *(const float4*)(wr + kk + lane * 4);
                a = fmaf(xv.x, wv.x, a); a = fmaf(xv.y, wv.y, a);
                a = fmaf(xv.z, wv.z, a); a = fmaf(xv.w, wv.w, a);
            }
#pragma unroll
            for (int off = 32; off >= 1; off >>= 1) a += __shfl_xor(a, off);
            if (lane == 0) lg[e] = a;
        }
        __syncthreads();
        if (w == 0) {
            const float logit = lg[lane];
            float m = logit;
#pragma unroll
            for (int off = 32; off >= 1; off >>= 1) m = fmaxf(m, __shfl_xor(m, off));
            const float ex = __expf(logit - m);
            float sum = ex;
#pragma unroll
            for (int off = 32; off >= 1; off >>= 1) sum += __shfl_xor(sum, off);
            const float score = ex / sum;
            float v = score;
            bool sel = false;
#pragma unroll
            for (int it = 0; it < 8; ++it) {
                float bv = v; int bi = lane;
#pragma unroll
                for (int off = 32; off >= 1; off >>= 1) {
                    const float ov = __shfl_xor(bv, off);
                    const int oi = __shfl_xor(bi, off);
                    if (ov > bv || (ov == bv && oi < bi)) { bv = ov; bi = oi; }
                }
                if (lane == bi) { sel = true; v = -1.f; }
            }
            out[(size_t)t * 64 + lane] = sel ? score : 0.f;
            out[(size_t)TOKENS * 64 + (size_t)t * 64 + lane] = sel ? 1.f : 0.f;
        }
        __syncthreads();
    }
}

// ---------------------------------------------------------------------------
extern "C" void kernel_launch(void* const* d_in, const int* in_sizes, int n_in,
                              void* d_out, int out_size, void* d_ws, size_t ws_size,
                              hipStream_t stream) {
    (void)in_sizes; (void)n_in; (void)out_size; (void)ws_size;
    const float* x = (const float*)d_in[0];       // [8192][4096] f32
    const float* w = (const float*)d_in[1];       // [64][4096] f32
    float* out = (float*)d_out;

    unsigned short* whb = (unsigned short*)d_ws;                       // 512 KB
    unsigned short* wlb = (unsigned short*)((char*)d_ws + (512 << 10)); // 512 KB
    int* flag_cnt = (int*)((char*)d_ws + (1 << 20));
    int* flag_list = (int*)((char*)d_ws + (1 << 20) + 64);

    hipMemsetAsync(flag_cnt, 0, sizeof(int), stream);
    prep_w<<<(EXPERTS * HIDDEN) / 256, 256, 0, stream>>>(w, whb, wlb);
    router_main<<<TOKENS / 32, 256, 0, stream>>>(x, whb, wlb, out,
                                                 flag_cnt, flag_list);
    router_rescue<<<256, 256, 0, stream>>>(x, w, out, flag_cnt, flag_list);
}